// Round 5
// baseline (348.213 us; speedup 1.0000x reference)
//
#include <hip/hip_runtime.h>
#include <hip/hip_bf16.h>
#include <math.h>

// ---------------------------------------------------------------------------
// ScatterSelfAttention, R5:
//  - attn: unroll 8 pairs (16 edges/batch) -> 8 outstanding uint4/lane,
//    one load batch covers the average degree (16). 32 lanes/edge, 2 edges
//    per wave-iter, no LDS.
//  - gemm1 stages f32 x directly (convert during LDS pack) -> convert_x gone
//  - prep kernel fuses cnt-zeroing + weight build -> 9 dispatches total
// ---------------------------------------------------------------------------

typedef __bf16 bf16x8 __attribute__((ext_vector_type(8)));
typedef float  f32x4  __attribute__((ext_vector_type(4)));

__device__ __forceinline__ ushort f32_to_bf16(float f) {
    uint u = __float_as_uint(f);
    u += 0x7FFF + ((u >> 16) & 1);          // RNE
    return (ushort)(u >> 16);
}
__device__ __forceinline__ uint pack_bf16x2(float a, float b) {
    return (uint)f32_to_bf16(a) | ((uint)f32_to_bf16(b) << 16);
}
__device__ __forceinline__ float bf_lo(uint w) { return __uint_as_float(w << 16); }
__device__ __forceinline__ float bf_hi(uint w) { return __uint_as_float(w & 0xFFFF0000u); }

// C[M,LDC] = A[M,128] @ Bt[LDC,128]_bf16^T + bias ; 128x64 tile, 4 waves.
// A_F32: A is f32 (guarded/clamped rows); else bf16 padded to 128-row multiple.
template<int LDC, bool OUT_BF16, bool A_F32>
__global__ __launch_bounds__(256) void gemm_mfma(
    const void* __restrict__ Av, const ushort* __restrict__ Bt,
    const float* __restrict__ bias, void* __restrict__ Cv, int M)
{
    __shared__ uint4 As4[2048];   // 128 rows x 16 chunks (8 bf16 each), XOR-swizzled
    __shared__ uint4 Bs4[1024];   // 64 rows x 16 chunks, XOR-swizzled
    const int tid  = threadIdx.x;
    const int wave = tid >> 6;
    const int lane = tid & 63;
    const int qd   = lane >> 4;     // 0..3
    const int ln   = lane & 15;
    const int rowBase = blockIdx.x * 128;
    const int colBase = blockIdx.y * 64;

    if (A_F32) {
        const float4* gx = (const float4*)Av;
        #pragma unroll
        for (int i = 0; i < 8; ++i) {
            int c  = tid + i * 256;                 // chunk id 0..2047
            int r  = rowBase + (c >> 4);
            if (r > M - 1) r = M - 1;               // clamp: no OOB on input buffer
            size_t f4 = (size_t)r * 32 + 2 * (c & 15);
            float4 lo = gx[f4], hi = gx[f4 + 1];
            uint4 pk;
            pk.x = pack_bf16x2(lo.x, lo.y);
            pk.y = pack_bf16x2(lo.z, lo.w);
            pk.z = pack_bf16x2(hi.x, hi.y);
            pk.w = pack_bf16x2(hi.z, hi.w);
            int lc = (c & ~15) | ((c ^ (c >> 4)) & 15);
            As4[lc] = pk;
        }
    } else {
        const uint4* gA = (const uint4*)((const ushort*)Av + (size_t)rowBase * 128);
        #pragma unroll
        for (int i = 0; i < 8; ++i) {
            int c  = tid + i * 256;
            int lc = (c & ~15) | ((c ^ (c >> 4)) & 15);
            As4[lc] = gA[c];
        }
    }
    const uint4* gB = (const uint4*)(Bt + (size_t)colBase * 128);
    #pragma unroll
    for (int i = 0; i < 4; ++i) {
        int c  = tid + i * 256;
        int lc = (c & ~15) | ((c ^ (c >> 4)) & 15);
        Bs4[lc] = gB[c];
    }
    __syncthreads();

    f32x4 acc[2][4];
    #pragma unroll
    for (int i = 0; i < 2; ++i)
        #pragma unroll
        for (int j = 0; j < 4; ++j)
            acc[i][j] = (f32x4){0.f, 0.f, 0.f, 0.f};

    const int m0 = wave * 32;
    #pragma unroll
    for (int ks = 0; ks < 4; ++ks) {
        const int kc = ks * 4 + qd;
        bf16x8 a0 = *((const bf16x8*)&As4[(m0 +      ln) * 16 + (kc ^ ln)]);
        bf16x8 a1 = *((const bf16x8*)&As4[(m0 + 16 + ln) * 16 + (kc ^ ln)]);
        bf16x8 b0 = *((const bf16x8*)&Bs4[(     ln) * 16 + (kc ^ ln)]);
        bf16x8 b1 = *((const bf16x8*)&Bs4[(16 + ln) * 16 + (kc ^ ln)]);
        bf16x8 b2 = *((const bf16x8*)&Bs4[(32 + ln) * 16 + (kc ^ ln)]);
        bf16x8 b3 = *((const bf16x8*)&Bs4[(48 + ln) * 16 + (kc ^ ln)]);
        acc[0][0] = __builtin_amdgcn_mfma_f32_16x16x32_bf16(a0, b0, acc[0][0], 0, 0, 0);
        acc[0][1] = __builtin_amdgcn_mfma_f32_16x16x32_bf16(a0, b1, acc[0][1], 0, 0, 0);
        acc[0][2] = __builtin_amdgcn_mfma_f32_16x16x32_bf16(a0, b2, acc[0][2], 0, 0, 0);
        acc[0][3] = __builtin_amdgcn_mfma_f32_16x16x32_bf16(a0, b3, acc[0][3], 0, 0, 0);
        acc[1][0] = __builtin_amdgcn_mfma_f32_16x16x32_bf16(a1, b0, acc[1][0], 0, 0, 0);
        acc[1][1] = __builtin_amdgcn_mfma_f32_16x16x32_bf16(a1, b1, acc[1][1], 0, 0, 0);
        acc[1][2] = __builtin_amdgcn_mfma_f32_16x16x32_bf16(a1, b2, acc[1][2], 0, 0, 0);
        acc[1][3] = __builtin_amdgcn_mfma_f32_16x16x32_bf16(a1, b3, acc[1][3], 0, 0, 0);
    }

    // C/D layout: col = lane&15, row = (lane>>4)*4 + reg
    #pragma unroll
    for (int i = 0; i < 2; ++i) {
        int rbase = rowBase + m0 + i * 16 + qd * 4;
        #pragma unroll
        for (int j = 0; j < 4; ++j) {
            int colg = colBase + j * 16 + ln;
            float bv = bias[colg];
            #pragma unroll
            for (int r = 0; r < 4; ++r) {
                int gr = rbase + r;
                if (gr < M) {
                    float val = acc[i][j][r] + bv;
                    if (OUT_BF16)
                        ((ushort*)Cv)[(size_t)gr * LDC + colg] = f32_to_bf16(val);
                    else
                        ((float*)Cv)[(size_t)gr * LDC + colg] = val;
                }
            }
        }
    }
}

// Fused: zero cnt + build WcatT (reordered, bf16), bcatI, WoT.
// Column order for Cb row (384 cols):
//   jj in [0,128)  -> q_jj
//   jj in [128,384): t = jj-128; chunk = t>>3 (= head*4+quad), pos = t&7
//                    col = head*16 + quad*4 + (pos&3); pos<4 -> K else V
__global__ void prep_kernel(
    const float* __restrict__ Wq, const float* __restrict__ Wk,
    const float* __restrict__ Wv, const float* __restrict__ bq,
    const float* __restrict__ bk, const float* __restrict__ bv,
    const float* __restrict__ Wo,
    ushort* __restrict__ WcatT, float* __restrict__ bcatI, ushort* __restrict__ WoT,
    int* __restrict__ cnt, int N)
{
    int idx = blockIdx.x * 256 + threadIdx.x;
    if (idx < N) cnt[idx] = 0;
    if (idx < 384 * 128) {
        int jj = idx >> 7, k = idx & 127;
        const float* W; int c;
        if (jj < 128) { W = Wq; c = jj; }
        else {
            int t = jj - 128;
            int chunk = t >> 3, pos = t & 7;
            int h = chunk >> 2, g = chunk & 3;
            c = h * 16 + g * 4 + (pos & 3);
            W = (pos < 4) ? Wk : Wv;
        }
        WcatT[idx] = f32_to_bf16(W[k * 128 + c]);
    } else if (idx < 384 * 128 + 384) {
        int jj = idx - 384 * 128;
        float b;
        if (jj < 128) b = bq[jj];
        else {
            int t = jj - 128;
            int chunk = t >> 3, pos = t & 7;
            int h = chunk >> 2, g = chunk & 3;
            int c = h * 16 + g * 4 + (pos & 3);
            b = (pos < 4) ? bk[c] : bv[c];
        }
        bcatI[jj] = b;
    } else if (idx < 384 * 128 + 384 + 128 * 128) {
        int t = idx - (384 * 128 + 384);
        int n = t >> 7, k = t & 127;
        WoT[t] = f32_to_bf16(Wo[k * 128 + n]);
    }
}

__global__ void hist_kernel(const int* __restrict__ dst, int* __restrict__ cnt, int E)
{
    int e = blockIdx.x * 256 + threadIdx.x;
    if (e < E) atomicAdd(&cnt[dst[e]], 1);
}

__global__ __launch_bounds__(256) void scan_block(const int* __restrict__ cnt,
                                                  int* __restrict__ incl,
                                                  int* __restrict__ bsum, int N)
{
    __shared__ int sd[256];
    int tid = threadIdx.x;
    int i = blockIdx.x * 256 + tid;
    int v = (i < N) ? cnt[i] : 0;
    sd[tid] = v;
    __syncthreads();
    #pragma unroll
    for (int o = 1; o < 256; o <<= 1) {
        int t = (tid >= o) ? sd[tid - o] : 0;
        __syncthreads();
        sd[tid] += t;
        __syncthreads();
    }
    if (i < N) incl[i] = sd[tid];
    if (tid == 255) bsum[blockIdx.x] = sd[255];
}

__global__ __launch_bounds__(256) void scan_top(int* __restrict__ bsum, int NB)
{
    __shared__ int sd[256];
    int tid = threadIdx.x;
    int v = (tid < NB) ? bsum[tid] : 0;
    sd[tid] = v;
    __syncthreads();
    #pragma unroll
    for (int o = 1; o < 256; o <<= 1) {
        int t = (tid >= o) ? sd[tid - o] : 0;
        __syncthreads();
        sd[tid] += t;
        __syncthreads();
    }
    if (tid < NB) bsum[tid] = sd[tid] - v;
}

__global__ void scan_finish(const int* __restrict__ cnt, const int* __restrict__ incl,
                            const int* __restrict__ bsum, int* __restrict__ off,
                            int N, int E)
{
    int i = blockIdx.x * 256 + threadIdx.x;
    if (i < N) off[i] = incl[i] - cnt[i] + bsum[i >> 8];
    if (i == 0) off[N] = E;
}

__global__ void scatter_kernel(const int* __restrict__ dst, int* __restrict__ cnt,
                               const int* __restrict__ off, int* __restrict__ eids, int E)
{
    int e = blockIdx.x * 256 + threadIdx.x;
    if (e < E) {
        int d = dst[e];
        int pos = atomicSub(&cnt[d], 1) - 1;
        eids[off[d] + pos] = e;
    }
}

// Process J pairs (2J edges) starting at pair index tbase.
template<int J>
__device__ __forceinline__ void attn_proc(
    const char* cb, const float* __restrict__ att_bias,
    float* __restrict__ logits_out,
    int regEid, uint regOff, int tbase, int e2, int c, int h,
    float q0, float q1, float q2, float q3,
    float& l, float& a0, float& a1, float& a2, float& a3)
{
    int e4[J]; uint o4[J]; uint4 w4[J]; float b4[J];
    #pragma unroll
    for (int j = 0; j < J; ++j) {
        int idx = 2 * (tbase + j) + e2;
        e4[j] = __shfl(regEid, idx);
        o4[j] = __shfl(regOff, idx);
    }
    #pragma unroll
    for (int j = 0; j < J; ++j) {
        w4[j] = *((const uint4*)(cb + o4[j]) + c);
        b4[j] = att_bias[e4[j] * 8 + h];
    }
    #pragma unroll
    for (int j = 0; j < J; ++j) {
        uint4 w = w4[j];
        float p = q0 * bf_lo(w.x) + q1 * bf_hi(w.x)
                + q2 * bf_lo(w.y) + q3 * bf_hi(w.y);
        p += __shfl_xor(p, 1);
        p += __shfl_xor(p, 2);
        float logit = p * 0.25f + b4[j];
        if ((c & 3) == 0) logits_out[e4[j] * 8 + h] = logit;
        float pe = __expf(logit);
        l += pe;
        a0 = fmaf(pe, bf_lo(w.z), a0); a1 = fmaf(pe, bf_hi(w.z), a1);
        a2 = fmaf(pe, bf_lo(w.w), a2); a3 = fmaf(pe, bf_hi(w.w), a3);
    }
}

// One wave per node, 4 nodes per 256-thread block. lane = e2*32 + c,
// c = head*4 + quad. One uint4 = (k quad | v quad) per lane per edge;
// parity halves process 2 edges per iteration. No LDS/barriers.
__global__ __launch_bounds__(256) void attn_kernel(
    const ushort* __restrict__ Cb, const int* __restrict__ off,
    const int* __restrict__ eids, const int* __restrict__ src_arr,
    const float* __restrict__ att_bias, float* __restrict__ logits_out,
    ushort* __restrict__ aggb, int N)
{
    const int wv   = threadIdx.x >> 6;
    const int lane = threadIdx.x & 63;
    const int node = blockIdx.x * 4 + wv;
    if (node >= N) return;
    const int e2 = lane >> 5;
    const int c  = lane & 31;      // head = c>>2, quad = c&3
    const int h  = c >> 2;

    uint2 qw = ((const uint2*)(Cb + (size_t)node * 384))[c];
    const float q0 = bf_lo(qw.x), q1 = bf_hi(qw.x);
    const float q2 = bf_lo(qw.y), q3 = bf_hi(qw.y);

    const int s = off[node];
    const int e = off[node + 1];
    const char* cb = (const char*)Cb;

    float l = 0.f, a0 = 0.f, a1 = 0.f, a2 = 0.f, a3 = 0.f;

    for (int b0 = s; b0 < e; b0 += 64) {
        const int cnt = min(64, e - b0);
        int gidx = b0 + ((lane < cnt) ? lane : (cnt - 1));
        int regEid = eids[gidx];
        uint regOff = (uint)src_arr[regEid] * 768u + 256u;   // byte off of kv region

        const int npairs = cnt >> 1;
        int t = 0;
        for (; t + 8 <= npairs; t += 8)
            attn_proc<8>(cb, att_bias, logits_out, regEid, regOff, t, e2, c, h,
                         q0, q1, q2, q3, l, a0, a1, a2, a3);
        if (t + 4 <= npairs) {
            attn_proc<4>(cb, att_bias, logits_out, regEid, regOff, t, e2, c, h,
                         q0, q1, q2, q3, l, a0, a1, a2, a3);
            t += 4;
        }
        if (t + 2 <= npairs) {
            attn_proc<2>(cb, att_bias, logits_out, regEid, regOff, t, e2, c, h,
                         q0, q1, q2, q3, l, a0, a1, a2, a3);
            t += 2;
        }
        if (t < npairs) {
            attn_proc<1>(cb, att_bias, logits_out, regEid, regOff, t, e2, c, h,
                         q0, q1, q2, q3, l, a0, a1, a2, a3);
        }
        if (cnt & 1) {                        // odd tail: parity 0 contributes
            int idx = cnt - 1;
            int  ei = __shfl(regEid, idx);
            uint of = __shfl(regOff, idx);
            uint4 w = *((const uint4*)(cb + of) + c);
            float bb = att_bias[ei * 8 + h];
            float p = q0 * bf_lo(w.x) + q1 * bf_hi(w.x)
                    + q2 * bf_lo(w.y) + q3 * bf_hi(w.y);
            p += __shfl_xor(p, 1);
            p += __shfl_xor(p, 2);
            float logit = p * 0.25f + bb;
            if ((c & 3) == 0 && e2 == 0) logits_out[ei * 8 + h] = logit;
            float pe = (e2 == 0) ? __expf(logit) : 0.f;
            l += pe;
            a0 = fmaf(pe, bf_lo(w.z), a0); a1 = fmaf(pe, bf_hi(w.z), a1);
            a2 = fmaf(pe, bf_lo(w.w), a2); a3 = fmaf(pe, bf_hi(w.w), a3);
        }
    }

    l  += __shfl_xor(l, 32);
    a0 += __shfl_xor(a0, 32);
    a1 += __shfl_xor(a1, 32);
    a2 += __shfl_xor(a2, 32);
    a3 += __shfl_xor(a3, 32);
    float inv = (l > 0.f) ? (1.f / l) : 0.f;
    if (e2 == 0) {
        uint2 o;
        o.x = pack_bf16x2(a0 * inv, a1 * inv);
        o.y = pack_bf16x2(a2 * inv, a3 * inv);
        ((uint2*)(aggb + (size_t)node * 128))[c] = o;   // cols 4c..4c+3
    }
}

extern "C" void kernel_launch(void* const* d_in, const int* in_sizes, int n_in,
                              void* d_out, int out_size, void* d_ws, size_t ws_size,
                              hipStream_t stream)
{
    const float* x        = (const float*)d_in[0];
    const int*   ei       = (const int*)d_in[1];   // [2,E]: dst row then src row
    const float* att_bias = (const float*)d_in[2];
    const float* Wq = (const float*)d_in[3];  const float* bq = (const float*)d_in[4];
    const float* Wk = (const float*)d_in[5];  const float* bk = (const float*)d_in[6];
    const float* Wv = (const float*)d_in[7];  const float* bv = (const float*)d_in[8];
    const float* Wo = (const float*)d_in[9];  const float* bo = (const float*)d_in[10];

    const int N = in_sizes[0] / 128;
    const int E = in_sizes[1] / 2;

    float* out    = (float*)d_out;               // [N,128]
    float* logits = out + (size_t)N * 128;       // [E,8]

    char* ws = (char*)d_ws;
    size_t o = 0;
    auto alloc = [&](size_t bytes) -> char* {
        char* p = ws + o;
        o = (o + bytes + 255) & ~(size_t)255;
        return p;
    };
    const int Mpad = ((N + 127) / 128) * 128;
    ushort* Cb    = (ushort*)alloc((size_t)N * 384 * 2);   // q | packed kv chunks
    ushort* aggb  = (ushort*)alloc((size_t)Mpad * 128 * 2);
    ushort* WcatT = (ushort*)alloc((size_t)384 * 128 * 2);
    float*  bcatI = (float*)alloc(384 * 4);
    ushort* WoT   = (ushort*)alloc((size_t)128 * 128 * 2);
    int*    cnt   = (int*)alloc((size_t)N * 4);
    int*    incl  = (int*)alloc((size_t)N * 4);
    const int NB  = (N + 255) / 256;
    int*    bsum  = (int*)alloc((size_t)NB * 4);
    int*    offp  = (int*)alloc((size_t)(N + 1) * 4);
    int*    eidsp = (int*)alloc((size_t)E * 4);

    const int nbN = (N + 255) / 256;
    const int nbE = (E + 255) / 256;
    const int MB  = (N + 127) / 128;

    const int prepTotal = 384 * 128 + 384 + 128 * 128;
    const int prepG = ((prepTotal > N ? prepTotal : N) + 255) / 256;
    prep_kernel<<<prepG, 256, 0, stream>>>(Wq, Wk, Wv, bq, bk, bv, Wo,
                                           WcatT, bcatI, WoT, cnt, N);

    dim3 g1(MB, 6);
    gemm_mfma<384, true, true><<<g1, 256, 0, stream>>>(x, WcatT, bcatI, Cb, N);

    hist_kernel<<<nbE, 256, 0, stream>>>(ei, cnt, E);
    scan_block<<<nbN, 256, 0, stream>>>(cnt, incl, bsum, N);
    scan_top<<<1, 256, 0, stream>>>(bsum, NB);
    scan_finish<<<nbN, 256, 0, stream>>>(cnt, incl, bsum, offp, N, E);
    scatter_kernel<<<nbE, 256, 0, stream>>>(ei, cnt, offp, eidsp, E);

    attn_kernel<<<(N + 3) / 4, 256, 0, stream>>>(Cb, offp, eidsp, ei + E, att_bias,
                                                 logits, aggb, N);

    dim3 g2(MB, 2);
    gemm_mfma<128, false, false><<<g2, 256, 0, stream>>>(aggb, WoT, bo, out, N);
}